// Round 12
// baseline (522.969 us; speedup 1.0000x reference)
//
#include <hip/hip_runtime.h>
#include <hip/hip_bf16.h>

typedef __attribute__((ext_vector_type(8))) short bf16x8;
typedef __attribute__((ext_vector_type(4))) float f32x4;
typedef __attribute__((ext_vector_type(2))) __bf16 bf16x2t;

#define MFMA(a, b, c) __builtin_amdgcn_mfma_f32_16x16x32_bf16(a, b, c, 0, 0, 0)

// f32 pair -> packed bf16x2 via native casts (RTNE; lowers to v_cvt_pk_bf16_f32)
__device__ __forceinline__ unsigned int pack2(float x, float y) {
  bf16x2t v;
  v.x = (__bf16)x; v.y = (__bf16)y;
  union { bf16x2t v; unsigned u; } c;
  c.v = v;
  return c.u;
}
__device__ __forceinline__ unsigned short f2bf(float x) {
  union { float f; unsigned u; } a{x};
  unsigned r = a.u + 0x7FFFu + ((a.u >> 16) & 1u);
  return (unsigned short)(r >> 16);
}
// pack two f32x4 (j=0..3 from a, j=4..7 from b) into one bf16x8 fragment
__device__ __forceinline__ bf16x8 pack8(f32x4 a, f32x4 b) {
  union { unsigned u[4]; bf16x8 v; } r;
  r.u[0] = pack2(a[0], a[1]); r.u[1] = pack2(a[2], a[3]);
  r.u[2] = pack2(b[0], b[1]); r.u[3] = pack2(b[2], b[3]);
  return r.v;
}

// token t (shifted-window order) -> flat pixel base offset (elements) in x / y
__device__ __forceinline__ int src_off(int t) {
  int wi = t >> 6, n = t & 63;
  int b = wi >> 10, wr = (wi >> 5) & 31, wc = wi & 31;
  int hh = (wr * 8 + (n >> 3) + 4) & 255;
  int ww = (wc * 8 + (n & 7) + 4) & 255;
  return ((((b << 8) | hh) << 8) | ww) << 8;
}

// ---- prep: weight transposes (bf16) + fragment-ordered relative bias ------
// rb2[h][mt][nt][g][ln][jr] = bias(q = 16*nt+ln, k = 16*mt+4*g+jr)  [S^T order]
__global__ __launch_bounds__(256) void prep_kernel(
    const float* __restrict__ w_qkv, const float* __restrict__ w_proj,
    const float* __restrict__ bias_table,
    unsigned short* __restrict__ wqkvt, unsigned short* __restrict__ wpt,
    float* __restrict__ rb2) {
  int i = blockIdx.x * 256 + threadIdx.x;
  if (i < 196608) {                        // wqkvt[n][k] = w_qkv[k][n]
    wqkvt[i] = f2bf(w_qkv[(i & 255) * 768 + (i >> 8)]);
  } else if (i < 262144) {                 // wpt[n][k] = w_proj[k][n]
    int j = i - 196608;
    wpt[j] = f2bf(w_proj[(j & 255) * 256 + (j >> 8)]);
  } else {
    int j = i - 262144;
    int jr = j & 3, ln = (j >> 2) & 15, g = (j >> 6) & 3;
    int nt = (j >> 8) & 3, mt = (j >> 10) & 3, h = j >> 12;
    int q = 16 * nt + ln;                  // query token
    int k = 16 * mt + 4 * g + jr;          // key token
    int idx = ((q >> 3) - (k >> 3) + 7) * 15 + ((q & 7) - (k & 7) + 7);
    rb2[j] = bias_table[idx * 8 + h];
  }
}

// ---- fused, 24-wave/CU variant: every live set <= ~85 regs ----------------
// LDS = 32 KiB XL only; AO overlays XL after all XL reads complete.
__global__ __launch_bounds__(512, 6) void fused_kernel(
    const float* __restrict__ x, const unsigned short* __restrict__ wqkvt,
    const float* __restrict__ b_qkv, const unsigned short* __restrict__ wpt,
    const float* __restrict__ b_proj, const float* __restrict__ rb2,
    float* __restrict__ y) {
  __shared__ unsigned short sm[16384];     // 32 KiB: XL, then per-wave AO overlay
  int wi = blockIdx.x;
  int tid = threadIdx.x;
  int h = tid >> 6, lane = tid & 63, ln = lane & 15, g = lane >> 4;
  int swl = (ln & 7) << 4;                 // overlay XOR swizzle (bits 4-6)

  // -------- phase 0: stage window x -> XL bf16 (swizzled) --------
  int tb = wi * 64;
  {
    int tok0 = tid >> 4, ck = tid & 15;
    int tok1 = tok0 + 32;
    const float4* s0 = (const float4*)(x + src_off(tb + tok0) + ck * 16);
    const float4* s1 = (const float4*)(x + src_off(tb + tok1) + ck * 16);
    float4 a0 = s0[0], a1 = s0[1], a2 = s0[2], a3 = s0[3];
    float4 b0 = s1[0], b1 = s1[1], b2 = s1[2], b3 = s1[3];
    uint4 w0, w1;
    w0.x = pack2(a0.x, a0.y); w0.y = pack2(a0.z, a0.w);
    w0.z = pack2(a1.x, a1.y); w0.w = pack2(a1.z, a1.w);
    w1.x = pack2(a2.x, a2.y); w1.y = pack2(a2.z, a2.w);
    w1.z = pack2(a3.x, a3.y); w1.w = pack2(a3.z, a3.w);
    int base0 = tok0 * 512 + ck * 32, swz0 = (tok0 & 7) << 4;
    *(uint4*)((char*)sm + ((base0) ^ swz0)) = w0;
    *(uint4*)((char*)sm + ((base0 + 16) ^ swz0)) = w1;
    w0.x = pack2(b0.x, b0.y); w0.y = pack2(b0.z, b0.w);
    w0.z = pack2(b1.x, b1.y); w0.w = pack2(b1.z, b1.w);
    w1.x = pack2(b2.x, b2.y); w1.y = pack2(b2.z, b2.w);
    w1.z = pack2(b3.x, b3.y); w1.w = pack2(b3.z, b3.w);
    int base1 = tok1 * 512 + ck * 32, swz1 = (tok1 & 7) << 4;
    *(uint4*)((char*)sm + ((base1) ^ swz1)) = w0;
    *(uint4*)((char*)sm + ((base1 + 16) ^ swz1)) = w1;
  }
  __syncthreads();

  // -------- pass Q (transposed: M = d, N = tokens); acc 32 regs --------
  bf16x8 qf[4];
  {
    f32x4 accq[2][4] = {};
#pragma unroll 1
    for (int ks = 0; ks < 8; ++ks) {
      bf16x8 xf[4];
#pragma unroll
      for (int t = 0; t < 4; ++t) {
        int row = 16 * t + ln;
        xf[t] = *(const bf16x8*)((char*)sm + ((row * 512 + ks * 64 + 16 * g) ^ ((row & 7) << 4)));
      }
      bf16x8 wq[2];
#pragma unroll
      for (int mt = 0; mt < 2; ++mt)
        wq[mt] = *(const bf16x8*)(wqkvt + (32 * h + 16 * mt + ln) * 256 + ks * 32 + 8 * g);
#pragma unroll
      for (int mt = 0; mt < 2; ++mt)
#pragma unroll
        for (int nt = 0; nt < 4; ++nt)
          accq[mt][nt] = MFMA(wq[mt], xf[nt], accq[mt][nt]);
    }
    const float sc = 0.17677669529663687f;
    f32x4 bq0 = *(const f32x4*)(b_qkv + 32 * h + 4 * g) * sc;
    f32x4 bq1 = *(const f32x4*)(b_qkv + 32 * h + 16 + 4 * g) * sc;
#pragma unroll
    for (int nt = 0; nt < 4; ++nt)
      qf[nt] = pack8(accq[0][nt] * sc + bq0, accq[1][nt] * sc + bq1);
  }

  // -------- pass K; acc 32 + qf 16 held --------
  bf16x8 kf[4];
  {
    f32x4 acck[2][4] = {};
#pragma unroll 1
    for (int ks = 0; ks < 8; ++ks) {
      bf16x8 xf[4];
#pragma unroll
      for (int t = 0; t < 4; ++t) {
        int row = 16 * t + ln;
        xf[t] = *(const bf16x8*)((char*)sm + ((row * 512 + ks * 64 + 16 * g) ^ ((row & 7) << 4)));
      }
      bf16x8 wk[2];
#pragma unroll
      for (int mt = 0; mt < 2; ++mt)
        wk[mt] = *(const bf16x8*)(wqkvt + (256 + 32 * h + 16 * mt + ln) * 256 + ks * 32 + 8 * g);
#pragma unroll
      for (int mt = 0; mt < 2; ++mt)
#pragma unroll
        for (int nt = 0; nt < 4; ++nt)
          acck[mt][nt] = MFMA(wk[mt], xf[nt], acck[mt][nt]);
    }
    f32x4 bk0 = *(const f32x4*)(b_qkv + 256 + 32 * h + 4 * g);
    f32x4 bk1 = *(const f32x4*)(b_qkv + 256 + 32 * h + 16 + 4 * g);
#pragma unroll
    for (int nt = 0; nt < 4; ++nt)
      kf[nt] = pack8(acck[0][nt] + bk0, acck[1][nt] + bk1);
  }

  // -------- pass V in dt-halves; av 16 regs each; vf packed direct --------
  bf16x8 vf[2][2];
#pragma unroll
  for (int dt = 0; dt < 2; ++dt) {
    f32x4 av[4] = {};
#pragma unroll 2
    for (int ks = 0; ks < 8; ++ks) {
      bf16x8 xf[4];
#pragma unroll
      for (int t = 0; t < 4; ++t) {
        int row = 16 * t + ln;
        xf[t] = *(const bf16x8*)((char*)sm + ((row * 512 + ks * 64 + 16 * g) ^ ((row & 7) << 4)));
      }
      bf16x8 wv = *(const bf16x8*)(wqkvt + (512 + 32 * h + 16 * dt + ln) * 256 + ks * 32 + 8 * g);
#pragma unroll
      for (int mt = 0; mt < 4; ++mt)
        av[mt] = MFMA(xf[mt], wv, av[mt]);
    }
    float bv = b_qkv[512 + 32 * h + 16 * dt + ln];
    f32x4 bvv = {bv, bv, bv, bv};
    // r7/r8-verified identity: pb's k-permutation == this pack order
    vf[0][dt] = pack8(av[0] + bvv, av[1] + bvv);
    vf[1][dt] = pack8(av[2] + bvv, av[3] + bvv);
  }
  __syncthreads();                         // all XL reads done -> overlay usable

  char* OVL = (char*)sm + h * 4096;        // per-wave AO [64 rows][64 B], swizzled
  const float* rbw = rb2 + h * 4096;

  // -------- attention in q-halves: st 32, pb 16, o 16 per half --------
#pragma unroll
  for (int H = 0; H < 2; ++H) {
    f32x4 st[4][2];
#pragma unroll
    for (int mt = 0; mt < 4; ++mt)
#pragma unroll
      for (int n = 0; n < 2; ++n)
        st[mt][n] = *(const f32x4*)(rbw + ((((mt * 4 + (2 * H + n)) * 4 + g) * 16 + ln) * 4));
#pragma unroll
    for (int mt = 0; mt < 4; ++mt)
#pragma unroll
      for (int n = 0; n < 2; ++n)
        st[mt][n] = MFMA(kf[mt], qf[2 * H + n], st[mt][n]);

    bf16x8 pb[2][2];
#pragma unroll
    for (int n = 0; n < 2; ++n) {
      f32x4 ma, mb;
#pragma unroll
      for (int jr = 0; jr < 4; ++jr) {
        ma[jr] = fmaxf(st[0][n][jr], st[1][n][jr]);
        mb[jr] = fmaxf(st[2][n][jr], st[3][n][jr]);
      }
      float mx = fmaxf(fmaxf(fmaxf(ma[0], mb[0]), fmaxf(ma[1], mb[1])),
                       fmaxf(fmaxf(ma[2], mb[2]), fmaxf(ma[3], mb[3])));
      mx = fmaxf(mx, __shfl_xor(mx, 16));
      mx = fmaxf(mx, __shfl_xor(mx, 32));
      f32x4 e0, e1, e2, e3;
#pragma unroll
      for (int jr = 0; jr < 4; ++jr) {
        e0[jr] = __expf(st[0][n][jr] - mx);
        e1[jr] = __expf(st[1][n][jr] - mx);
        e2[jr] = __expf(st[2][n][jr] - mx);
        e3[jr] = __expf(st[3][n][jr] - mx);
      }
      f32x4 s01 = e0 + e1, s23 = e2 + e3;
      float sum = (s01[0] + s23[0]) + (s01[1] + s23[1])
                + ((s01[2] + s23[2]) + (s01[3] + s23[3]));
      sum += __shfl_xor(sum, 16);
      sum += __shfl_xor(sum, 32);
      float inv = 1.f / sum;
      pb[0][n] = pack8(e0 * inv, e1 * inv);
      pb[1][n] = pack8(e2 * inv, e3 * inv);
    }

    f32x4 o[2][2] = {};
#pragma unroll
    for (int kk = 0; kk < 2; ++kk)
#pragma unroll
      for (int dt = 0; dt < 2; ++dt)
#pragma unroll
        for (int n = 0; n < 2; ++n)
          o[dt][n] = MFMA(vf[kk][dt], pb[kk][n], o[dt][n]);

    // AO write: row q = 16*(2H+n)+ln (64 B pitch), col byte 32dt+8g, XOR swl
#pragma unroll
    for (int dt = 0; dt < 2; ++dt)
#pragma unroll
      for (int n = 0; n < 2; ++n) {
        uint2 vp;
        vp.x = pack2(o[dt][n][0], o[dt][n][1]);
        vp.y = pack2(o[dt][n][2], o[dt][n][3]);
        int byte = ((16 * (2 * H + n) + ln) * 64 + 32 * dt + 8 * g) ^ swl;
        *(uint2*)(OVL + byte) = vp;
      }
  }
  __syncthreads();

  // -------- proj: K-step ks = head ks's AO overlay region --------
  f32x4 a2[4][2] = {};
#pragma unroll 2
  for (int ks = 0; ks < 8; ++ks) {
    const char* AO = (const char*)sm + ks * 4096;
    bf16x8 af2[4], bf2[2];
#pragma unroll
    for (int mt = 0; mt < 4; ++mt)
      af2[mt] = *(const bf16x8*)(AO + (((16 * mt + ln) * 64 + 16 * g) ^ swl));
#pragma unroll
    for (int nt = 0; nt < 2; ++nt)
      bf2[nt] = *(const bf16x8*)(wpt + (32 * h + 16 * nt + ln) * 256 + ks * 32 + 8 * g);
#pragma unroll
    for (int mt = 0; mt < 4; ++mt) {
      a2[mt][0] = MFMA(af2[mt], bf2[0], a2[mt][0]);
      a2[mt][1] = MFMA(af2[mt], bf2[1], a2[mt][1]);
    }
  }
  // epilogue: un-shift scatter + proj bias (hoisted bases)
  int b = wi >> 10, wr = (wi >> 5) & 31, wc = wi & 31;
  int hb = wr * 8 + (g >> 1) + 4;
  int wb = wc * 8 + 4 * (g & 1) + 4;
  int colb = 32 * h + ln;
  float bp0 = b_proj[colb], bp1 = b_proj[colb + 16];
#pragma unroll
  for (int mt = 0; mt < 4; ++mt) {
    int hh = (hb + 2 * mt) & 255;
#pragma unroll
    for (int jr = 0; jr < 4; ++jr) {
      int ww = (wb + jr) & 255;
      float* yp = y + (((((b << 8) | hh) << 8) | ww) << 8) + colb;
      yp[0]  = a2[mt][0][jr] + bp0;
      yp[16] = a2[mt][1][jr] + bp1;
    }
  }
}

extern "C" void kernel_launch(void* const* d_in, const int* in_sizes, int n_in,
                              void* d_out, int out_size, void* d_ws, size_t ws_size,
                              hipStream_t stream) {
  const float* x          = (const float*)d_in[0];
  const float* w_qkv      = (const float*)d_in[1];
  const float* b_qkv      = (const float*)d_in[2];
  const float* w_proj     = (const float*)d_in[3];
  const float* b_proj     = (const float*)d_in[4];
  const float* bias_table = (const float*)d_in[5];
  char* ws = (char*)d_ws;
  // ws layout: wqkvt 384 KiB | wpt 128 KiB | rb2 128 KiB
  unsigned short* wqkvt = (unsigned short*)(ws);
  unsigned short* wpt   = (unsigned short*)(ws + 393216);
  float* rb2            = (float*)(ws + 524288);
  float* y = (float*)d_out;

  prep_kernel<<<1152, 256, 0, stream>>>(w_qkv, w_proj, bias_table, wqkvt, wpt, rb2);
  fused_kernel<<<4096, 512, 0, stream>>>(x, wqkvt, b_qkv, wpt, b_proj, rb2, y);
}